// Round 8
// baseline (254.018 us; speedup 1.0000x reference)
//
#include <hip/hip_runtime.h>
#include <hip/hip_bf16.h>

typedef __hip_bfloat16 bf16;
typedef __attribute__((ext_vector_type(8))) short short8;   // 8 bf16 = 4 VGPR
typedef __attribute__((ext_vector_type(4))) float f32x4;

#define HWP 3136
#define WD 56
#define PW 58          // padded width (1-px zero border)
#define PADP 3364      // 58*58
#define CC 128
#define MIDM 32
#define OGN 512
#define NB 4

// workspace offsets in FLOAT units (all multiples of 4 -> 16B aligned)
enum : int {
  OFF_FLAG = 0,                          // [4]
  OFF_W2F  = 4,                          // fp32 [o][m] 512x32
  OFF_SC2  = OFF_W2F + OGN*MIDM,         // [32]
  OFF_SH2  = OFF_SC2 + MIDM,             // [32]
  OFF_B1F  = OFF_SH2 + MIDM,             // [32]
  OFF_B2F  = OFF_B1F + MIDM,             // [512]
  OFF_GNG  = OFF_B2F + OGN,              // [512]
  OFF_GNB  = OFF_GNG + OGN,              // [512]
  OFF_GPART= OFF_GNB + OGN,              // fp32 [b][128][1056] Gram+S1 partials
  OFF_PQ   = OFF_GPART + NB*128*1056,    // float2 [b][512]
  OFF_SS1  = OFF_PQ + NB*OGN*2,          // float2 [128]
  OFF_SSV  = OFF_SS1 + CC*2,             // float2 [512]
  OFF_WKB  = OFF_SSV + OGN*2,            // bf16 [d][c] 128x128
  OFF_WVB  = OFF_WKB + CC*CC/2,          // bf16 [o][c] 512x128
  OFF_W1AB = OFF_WVB + OGN*CC/2,         // bf16 [m][c] 32x128
  OFF_W1BB = OFF_W1AB + MIDM*CC/2,       // bf16 [m][c] 32x128
  OFF_HQT  = OFF_W1BB + MIDM*CC/2,       // bf16 [b][pix][m] (unpadded)
  OFF_GKT  = OFF_HQT + NB*HWP*MIDM/2,    // bf16 [b][pp58][m] PADDED, zero border
  OFF_AB   = OFF_GKT + NB*PADP*MIDM/2,   // bf16 [b][o][m]  (dedicated: xt stays live)
  OFF_XT   = OFF_AB + NB*OGN*MIDM/2,     // bf16 [b][pix][c] (live prep -> out)
  WS_TOTAL = OFF_XT + NB*HWP*CC/2        // ~8 MB
};

__device__ __forceinline__ float b2f(unsigned short u) {
  bf16 h; *(unsigned short*)&h = u; return __bfloat162float(h);
}
__device__ __forceinline__ unsigned short f2b(float f) {
  bf16 h = __float2bfloat16(f); return *(unsigned short*)&h;
}
__device__ __forceinline__ float ldmix(const void* p, size_t i, bool isbf) {
  return isbf ? __bfloat162float(((const bf16*)p)[i]) : ((const float*)p)[i];
}
__device__ __forceinline__ f32x4 mfma16(short8 a, short8 b, f32x4 c) {
  return __builtin_amdgcn_mfma_f32_16x16x32_bf16(a, b, c, 0, 0, 0);
}
__device__ __forceinline__ bool detect_bf(const unsigned short* xr) {
  int cnt = 0;
#pragma unroll
  for (int i = 0; i < 32; i++) {
    short8 v = *(const short8*)(xr + i*8);
#pragma unroll
    for (int j = 0; j < 8; j++) {
      int e = (((unsigned short)v[j]) >> 7) & 0xFF;
      cnt += (e >= 141) ? 1 : 0;
    }
  }
  return cnt < 8;
}

// ---- L1: detect + params + x->xt transpose (blocks 0..391) + gkt zero ----
__global__ __launch_bounds__(256) void k_prep(
    const void* __restrict__ x,  const void* __restrict__ Wk,
    const void* __restrict__ bn1_g, const void* __restrict__ bn1_b,
    const void* __restrict__ bn1_m, const void* __restrict__ bn1_v,
    const void* __restrict__ W1, const void* __restrict__ b1,
    const void* __restrict__ bn2_g, const void* __restrict__ bn2_b,
    const void* __restrict__ bn2_m, const void* __restrict__ bn2_v,
    const void* __restrict__ W2, const void* __restrict__ b2,
    const void* __restrict__ gn_g, const void* __restrict__ gn_b,
    const void* __restrict__ Wv,
    const void* __restrict__ bnv_g, const void* __restrict__ bnv_b,
    const void* __restrict__ bnv_m, const void* __restrict__ bnv_v,
    float* __restrict__ ws) {
  __shared__ unsigned short tile[32*130];
  const bool isbf = detect_bf((const unsigned short*)x);
  int blk = blockIdx.x, tid = threadIdx.x;
  if (blk == 0 && tid == 0) ws[OFF_FLAG] = isbf ? 1.f : 0.f;
  int gid = blk*256 + tid, gstride = gridDim.x*256;
  unsigned short* wkb = (unsigned short*)(ws + OFF_WKB);
  unsigned short* wvb = (unsigned short*)(ws + OFF_WVB);
  unsigned short* w1ab = (unsigned short*)(ws + OFF_W1AB);
  unsigned short* w1bb = (unsigned short*)(ws + OFF_W1BB);
  float2* ss1 = (float2*)(ws + OFF_SS1);
  float2* ssv = (float2*)(ws + OFF_SSV);
  for (int i = gid; i < CC*CC; i += gstride) wkb[i] = f2b(ldmix(Wk, i, isbf));
  for (int i = gid; i < OGN*CC; i += gstride) wvb[i] = f2b(ldmix(Wv, i, isbf));
  for (int i = gid; i < MIDM*CC; i += gstride) {
    int m = i / CC, c = i % CC;
    w1ab[i] = f2b(ldmix(W1, (size_t)m*(2*CC) + c, isbf));
    w1bb[i] = f2b(ldmix(W1, (size_t)m*(2*CC) + CC + c, isbf));
  }
  for (int i = gid; i < OGN*MIDM; i += gstride) ws[OFF_W2F + i] = ldmix(W2, i, isbf);
  for (int i = gid; i < CC; i += gstride) {
    float s = ldmix(bn1_g, i, isbf) / sqrtf(ldmix(bn1_v, i, isbf) + 1e-5f);
    ss1[i] = make_float2(s, ldmix(bn1_b, i, isbf) - ldmix(bn1_m, i, isbf) * s);
  }
  for (int i = gid; i < MIDM; i += gstride) {
    float s = ldmix(bn2_g, i, isbf) / sqrtf(ldmix(bn2_v, i, isbf) + 1e-5f);
    ws[OFF_SC2 + i] = s;
    ws[OFF_SH2 + i] = ldmix(bn2_b, i, isbf) - ldmix(bn2_m, i, isbf)*s;
    ws[OFF_B1F + i] = ldmix(b1, i, isbf);
  }
  for (int i = gid; i < OGN; i += gstride) {
    float s = ldmix(bnv_g, i, isbf) / sqrtf(ldmix(bnv_v, i, isbf) + 1e-5f);
    ssv[i] = make_float2(s, ldmix(bnv_b, i, isbf) - ldmix(bnv_m, i, isbf) * s);
    ws[OFF_B2F + i] = ldmix(b2, i, isbf);
    ws[OFF_GNG + i] = ldmix(gn_g, i, isbf);
    ws[OFF_GNB + i] = ldmix(gn_b, i, isbf);
  }
  if (blk < 392) {
    int b = blk / 98, pix0 = (blk % 98)*32;
#pragma unroll
    for (int k = 0; k < 16; k++) {
      int idx = tid + k*256;
      int c = idx >> 5, pl = idx & 31;
      tile[pl*130 + c] = f2b(ldmix(x, ((size_t)b*CC + c)*HWP + pix0 + pl, isbf));
    }
    __syncthreads();
    unsigned short* xt = (unsigned short*)(ws + OFF_XT);
#pragma unroll
    for (int k = 0; k < 16; k++) {
      int idx = tid + k*256;
      int c = idx & 127, pl = idx >> 7;
      xt[((size_t)b*HWP + pix0 + pl)*CC + c] = tile[pl*130 + c];
    }
  } else {
    // zero whole gkt_pad
    const int NG = NB*PADP*4;
    const short8 z = {0,0,0,0,0,0,0,0};
    unsigned short* gk = (unsigned short*)(ws + OFF_GKT);
    for (int u = (blk-392)*256 + tid; u < NG; u += 28*256) {
      int b = u / (PADP*4), rem = u - b*(PADP*4);
      int pp = rem >> 2, mch = rem & 3;
      *(short8*)(gk + ((size_t)b*PADP + pp)*MIDM + mch*8) = z;
    }
  }
}

// ---- L2: keq only (v-part fused into k_out). grid 196. ----
__global__ __launch_bounds__(256, 4) void k_mid(float* __restrict__ ws) {
  __shared__ unsigned short keL[4][16][136];
  int bid = blockIdx.x, tid = threadIdx.x;
  int w = tid >> 6, lane = tid & 63, q = lane >> 4, l16 = lane & 15;
  int b = bid / 49, bx = bid - (bid/49)*49;
  int pix = bx*64 + w*16 + l16;
  const unsigned short* xt = (const unsigned short*)(ws + OFF_XT) + ((size_t)b*HWP + pix)*CC;
  short8 Bx[4];
#pragma unroll
  for (int kk = 0; kk < 4; kk++) Bx[kk] = *(const short8*)(xt + kk*32 + q*8);
  const unsigned short* wkb = (const unsigned short*)(ws + OFF_WKB);
  const float2* ss = (const float2*)(ws + OFF_SS1);
#pragma unroll
  for (int ot = 0; ot < 8; ot++) {
    int drow = ot*16 + l16;
    f32x4 c = {0.f, 0.f, 0.f, 0.f};
#pragma unroll
    for (int kk = 0; kk < 4; kk++)
      c = mfma16(*(const short8*)(wkb + (size_t)drow*CC + kk*32 + q*8), Bx[kk], c);
    int d0 = ot*16 + q*4;
    ushort4 st;
    { float2 s = ss[d0+0]; st.x = f2b(fmaxf(s.x*c[0] + s.y, 0.f)); }
    { float2 s = ss[d0+1]; st.y = f2b(fmaxf(s.x*c[1] + s.y, 0.f)); }
    { float2 s = ss[d0+2]; st.z = f2b(fmaxf(s.x*c[2] + s.y, 0.f)); }
    { float2 s = ss[d0+3]; st.w = f2b(fmaxf(s.x*c[3] + s.y, 0.f)); }
    *(ushort4*)&keL[w][l16][d0] = st;
  }
  __syncthreads();
  short8 Bk[4];
#pragma unroll
  for (int kk = 0; kk < 4; kk++) Bk[kk] = *(const short8*)&keL[w][l16][kk*32 + q*8];
  const unsigned short* w1a = (const unsigned short*)(ws + OFF_W1AB);
  const unsigned short* w1b = (const unsigned short*)(ws + OFF_W1BB);
  int h0 = pix / WD, w0 = pix - h0*WD;
  int pp = (h0+1)*PW + (w0+1);
  unsigned short* hqt = (unsigned short*)(ws + OFF_HQT) + ((size_t)b*HWP + pix)*MIDM;
  unsigned short* gkt = (unsigned short*)(ws + OFF_GKT) + ((size_t)b*PADP + pp)*MIDM;
#pragma unroll
  for (int mt = 0; mt < 2; mt++) {
    int mrow = mt*16 + l16;
    f32x4 ch = {0.f,0.f,0.f,0.f}, cg = {0.f,0.f,0.f,0.f};
#pragma unroll
    for (int kk = 0; kk < 4; kk++) {
      ch = mfma16(*(const short8*)(w1a + (size_t)mrow*CC + kk*32 + q*8), Bx[kk], ch);
      cg = mfma16(*(const short8*)(w1b + (size_t)mrow*CC + kk*32 + q*8), Bk[kk], cg);
    }
    int m0 = mt*16 + q*4;
    ushort4 sh, sg;
    sh.x = f2b(ch[0]); sh.y = f2b(ch[1]); sh.z = f2b(ch[2]); sh.w = f2b(ch[3]);
    sg.x = f2b(cg[0]); sg.y = f2b(cg[1]); sg.z = f2b(cg[2]); sg.w = f2b(cg[3]);
    *(ushort4*)(hqt + m0) = sh;
    *(ushort4*)(gkt + m0) = sg;
  }
}

// ---- L3: Gram/S1 partials only (k_out recomputes hs). grid (32,4). ----
__global__ __launch_bounds__(256) void k_gramh(float* __restrict__ ws) {
  __shared__ unsigned short tileT[32][264];
  int b = blockIdx.y, bk = blockIdx.x;
  int tid = threadIdx.x;
  int w = tid >> 6, lane = tid & 63, q = lane >> 4, l16 = lane & 15;
  const int base = bk * 882;                 // 28224 / 32
  const unsigned short* hqt = (const unsigned short*)(ws + OFF_HQT) + (size_t)b*HWP*MIDM;
  const unsigned short* gkp = (const unsigned short*)(ws + OFF_GKT) + (size_t)b*PADP*MIDM;
  float sc2[MIDM], bas0[MIDM];
#pragma unroll
  for (int m = 0; m < MIDM; m++) {
    sc2[m] = ws[OFF_SC2 + m];
    bas0[m] = sc2[m]*ws[OFF_B1F + m] + ws[OFF_SH2 + m];
  }
  f32x4 gLL={0,0,0,0}, gLH={0,0,0,0}, gHH={0,0,0,0}, sL={0,0,0,0}, sH={0,0,0,0};
  short8 ones;
#pragma unroll
  for (int j = 0; j < 8; j++) ones[j] = (short)0x3F80;
  for (int t = 0; t < 4; t++) {
    int r = t*256 + tid;
    bool valid = r < 882;
    int R = valid ? (base + r) : 0;
    int p = R / HWP, pix = R - p*HWP;
    int h0 = pix / WD, w0 = pix - h0*WD;
    int npp = (h0 + p/3)*PW + (w0 + p - (p/3)*3);
    const unsigned short* hq = hqt + (size_t)pix*MIDM;
    const unsigned short* gk = gkp + (size_t)npp*MIDM;
#pragma unroll
    for (int ch = 0; ch < 4; ch++) {
      short8 th = *(const short8*)(hq + ch*8);
      short8 tg = *(const short8*)(gk + ch*8);
      short8 o;
#pragma unroll
      for (int j = 0; j < 8; j++) {
        int m = ch*8 + j;
        float hv = b2f((unsigned short)th[j]) + b2f((unsigned short)tg[j]);
        float v = fmaxf(sc2[m]*hv + bas0[m], 0.f);
        o[j] = valid ? (short)f2b(v) : (short)0;
      }
#pragma unroll
      for (int j = 0; j < 8; j++) tileT[ch*8 + j][tid] = (unsigned short)o[j];
    }
    __syncthreads();
#pragma unroll
    for (int cc = 0; cc < 2; cc++) {
      int c = w*2 + cc;
      short8 alo = *(const short8*)&tileT[l16][c*32 + q*8];
      short8 ahi = *(const short8*)&tileT[l16+16][c*32 + q*8];
      gLL = mfma16(alo, alo, gLL);
      gLH = mfma16(alo, ahi, gLH);
      gHH = mfma16(ahi, ahi, gHH);
      sL = mfma16(alo, ones, sL);
      sH = mfma16(ahi, ones, sH);
    }
    __syncthreads();
  }
  float* blob = ws + OFF_GPART + ((size_t)((b*32 + bk)*4 + w))*1056;
#pragma unroll
  for (int r = 0; r < 4; r++) {
    int row = q*4 + r;
    blob[row*32 + l16]             = gLL[r];
    blob[row*32 + 16 + l16]        = gLH[r];
    blob[(16 + l16)*32 + row]      = gLH[r];   // HL = LH^T
    blob[(16 + row)*32 + 16 + l16] = gHH[r];
  }
  if (l16 == 0) {
#pragma unroll
    for (int r = 0; r < 4; r++) {
      blob[1024 + q*4 + r]      = sL[r];
      blob[1024 + 16 + q*4 + r] = sH[r];
    }
  }
}

// ---- L4: GN stats -> PQ + precompute AB = f2b(alpha*W2). grid (4) x 512 ----
__global__ __launch_bounds__(512) void k_stats(float* __restrict__ ws) {
  __shared__ float Gs[MIDM*MIDM], S1s[MIDM], saS[OGN], sqS[OGN], muS[128], invS[128];
  int b = blockIdx.x, o = threadIdx.x;
  for (int e = o; e < 1056; e += 512) {
    float s = 0.f;
    const float* pb = ws + OFF_GPART + (size_t)b*128*1056 + e;
    for (int p = 0; p < 128; p++) s += pb[(size_t)p*1056];
    if (e < 1024) Gs[e] = s; else S1s[e - 1024] = s;
  }
  __syncthreads();
  float w2[MIDM];
#pragma unroll
  for (int m = 0; m < MIDM; m++) w2[m] = ws[OFF_W2F + o*MIDM + m];
  float dotS = 0.f;
#pragma unroll
  for (int m = 0; m < MIDM; m++) dotS += w2[m] * S1s[m];
  float quad = 0.f;
  for (int a = 0; a < MIDM; a++) {
    float t = 0.f;
#pragma unroll
    for (int c = 0; c < MIDM; c++) t += Gs[a*MIDM + c] * w2[c];
    quad += w2[a] * t;
  }
  float b2o = ws[OFF_B2F + o];
  const float M = 9.f * HWP;
  saS[o] = dotS + b2o * M;
  sqS[o] = quad + 2.f*b2o*dotS + b2o*b2o*M;
  __syncthreads();
  if (o < 128) {
    float sa = saS[4*o] + saS[4*o+1] + saS[4*o+2] + saS[4*o+3];
    float sq = sqS[4*o] + sqS[4*o+1] + sqS[4*o+2] + sqS[4*o+3];
    const float invN = 1.f / (4.f * M);
    float mu = sa * invN;
    float var = sq * invN - mu*mu;
    muS[o] = mu;
    invS[o] = 1.f / sqrtf(var + 1e-5f);
  }
  __syncthreads();
  int co = o >> 2;
  float alpha = ws[OFF_GNG + o] * invS[co];
  ((float2*)(ws + OFF_PQ))[b*OGN + o] =
      make_float2(alpha, alpha*b2o + ws[OFF_GNB + o] - muS[co]*alpha);
  unsigned short* dst = (unsigned short*)(ws + OFF_AB) + ((size_t)b*OGN + o)*MIDM;
#pragma unroll
  for (int m = 0; m < MIDM; m += 4) {
    ushort4 t;
    t.x = f2b(alpha*w2[m+0]); t.y = f2b(alpha*w2[m+1]);
    t.z = f2b(alpha*w2[m+2]); t.w = f2b(alpha*w2[m+3]);
    *(ushort4*)(dst + m) = t;
  }
}

// ---- L5: epilogue, fused V-in-LDS, 64-o windows for occupancy:
//      256 rows x 64 o per block (LDS 34.8 KB -> 4 blocks/CU, 16 waves/CU).
//      V-build chain per wave halves vs r7 (64 MFMA). grid (25,8,4)=800. ----
#define VST2 68   // u16 row stride for 64-o window (136 B, bank stride 2)
__global__ __launch_bounds__(256, 4) void k_out(const float* __restrict__ ws,
                                                void* __restrict__ outp) {
  __shared__ unsigned short tileV[256*VST2];   // 34.8 KB
  int b = blockIdx.z, by = blockIdx.y;         // by in [0,8): o-base by*64
  int bx = blockIdx.x;                         // 0..24: 128-px double strip
  int tid = threadIdx.x;
  int w = tid >> 6, lane = tid & 63, q = lane >> 4, l16 = lane & 15;
  int pix0 = bx*128;
  int h00 = pix0 / WD, w00 = pix0 - h00*WD;
  int wstart = (h00+1)*PW + (w00+1) - (PW+1);
  const bool hasB = (bx < 24);
  int pixA = pix0 + w*16 + l16;
  // per-m constants for hs recompute
  float sc[8], ba[8];
#pragma unroll
  for (int j = 0; j < 8; j++) {
    int m = q*8 + j;
    sc[j] = ws[OFF_SC2 + m];
    ba[j] = sc[j]*ws[OFF_B1F + m] + ws[OFF_SH2 + m];
  }
  const unsigned short* hqt = (const unsigned short*)(ws + OFF_HQT) + (size_t)b*HWP*MIDM;
  const unsigned short* gkt = (const unsigned short*)(ws + OFF_GKT) + (size_t)b*PADP*MIDM;
  // ---- strip A hs fragments ----
  int hA = pixA / WD, wA = pixA - hA*WD;
  short8 BfA[9];
  {
    short8 th = *(const short8*)(hqt + (size_t)pixA*MIDM + q*8);
    float hv[8];
#pragma unroll
    for (int j = 0; j < 8; j++) hv[j] = b2f((unsigned short)th[j]);
    const unsigned short* gkb = gkt + ((size_t)hA*PW + wA)*MIDM + q*8;
#pragma unroll
    for (int p = 0; p < 9; p++) {
      short8 tg = *(const short8*)(gkb + (size_t)((p/3)*PW + (p - (p/3)*3))*MIDM);
#pragma unroll
      for (int j = 0; j < 8; j++)
        BfA[p][j] = (short)f2b(fmaxf(sc[j]*(hv[j] + b2f((unsigned short)tg[j])) + ba[j], 0.f));
    }
  }
  // ---- build V window in LDS: 256 pp rows x 64 o (fused Wv matmul + bnv) ----
  {
    const unsigned short* xtb = (const unsigned short*)(ws + OFF_XT) + (size_t)b*HWP*CC;
    const unsigned short* wvb = (const unsigned short*)(ws + OFF_WVB);
    const float2* ssv = (const float2*)(ws + OFF_SSV);
#pragma unroll
    for (int g = 0; g < 4; g++) {
      int wr = w*64 + g*16 + l16;               // window row 0..255
      int pp = wstart + wr;
      int ph = pp / PW, pw = pp - ph*PW;
      bool inter = (ph >= 1) && (ph <= WD) && (pw >= 1) && (pw <= WD);
      int pixel = (ph-1)*WD + (pw-1);
      short8 Bx[4];
      if (inter) {
        const unsigned short* xr = xtb + (size_t)pixel*CC + q*8;
#pragma unroll
        for (int kk = 0; kk < 4; kk++) Bx[kk] = *(const short8*)(xr + kk*32);
      } else {
        const short8 z = {0,0,0,0,0,0,0,0};
#pragma unroll
        for (int kk = 0; kk < 4; kk++) Bx[kk] = z;
      }
#pragma unroll
      for (int ot = 0; ot < 4; ot++) {
        int orow = by*64 + ot*16 + l16;
        f32x4 c = {0.f, 0.f, 0.f, 0.f};
#pragma unroll
        for (int kk = 0; kk < 4; kk++)
          c = mfma16(*(const short8*)(wvb + (size_t)orow*CC + kk*32 + q*8), Bx[kk], c);
        int o0 = by*64 + ot*16 + q*4;
        ushort4 st;
        if (inter) {
          float2 s0 = ssv[o0+0], s1 = ssv[o0+1], s2 = ssv[o0+2], s3 = ssv[o0+3];
          st.x = f2b(s0.x*c[0] + s0.y); st.y = f2b(s1.x*c[1] + s1.y);
          st.z = f2b(s2.x*c[2] + s2.y); st.w = f2b(s3.x*c[3] + s3.y);
        } else { st.x = 0; st.y = 0; st.z = 0; st.w = 0; }
        *(ushort4*)&tileV[wr*VST2 + ot*16 + q*4] = st;
      }
    }
  }
  const bool isbf = ws[OFF_FLAG] > 0.5f;
  const float2* pq = (const float2*)(ws + OFF_PQ) + b*OGN;
  const unsigned short* ABb = (const unsigned short*)(ws + OFF_AB)
      + ((size_t)b*OGN + by*64)*MIDM;
  const int doff[9] = {-PW-1, -PW, -PW+1, -1, 0, 1, PW-1, PW, PW+1};
  int pplA = (hA+1)*PW + (wA+1) - wstart;
  // A-fragments + Qv (single 64-o tile)
  short8 A[4];
  f32x4 Qv[4];
#pragma unroll
  for (int ot = 0; ot < 4; ot++) {
    A[ot] = *(const short8*)(ABb + (size_t)(ot*16 + l16)*MIDM + q*8);
    int o0 = by*64 + ot*16 + q*4;
    f32x4 qv = { pq[o0+0].y, pq[o0+1].y, pq[o0+2].y, pq[o0+3].y };
    Qv[ot] = qv;
  }
  __syncthreads();
  // ---- strip A ----
  {
    float acc[4] = {0.f, 0.f, 0.f, 0.f};
#pragma unroll
    for (int p = 0; p < 9; p++) {
      int lp = pplA + doff[p];
      const unsigned short* vrow = &tileV[lp*VST2];
#pragma unroll
      for (int ot = 0; ot < 4; ot++) {
        f32x4 c = {0.f, 0.f, 0.f, 0.f};
        c = mfma16(A[ot], BfA[p], c);
        ushort4 vv = *(const ushort4*)(vrow + ot*16 + q*4);
        acc[ot] += (c[0] + Qv[ot][0])*b2f(vv.x) + (c[1] + Qv[ot][1])*b2f(vv.y)
                 + (c[2] + Qv[ot][2])*b2f(vv.z) + (c[3] + Qv[ot][3])*b2f(vv.w);
      }
    }
#pragma unroll
    for (int ot = 0; ot < 4; ot++) {
      int co = by*16 + ot*4 + q;
      size_t oidx = ((size_t)b*128 + co)*HWP + pixA;
      if (isbf) __builtin_nontemporal_store(f2b(acc[ot]), (unsigned short*)outp + oidx);
      else      __builtin_nontemporal_store(acc[ot], (float*)outp + oidx);
    }
  }
  // ---- strip B ----
  if (hasB) {
    int pixB = pixA + 64;
    int hB = pixB / WD, wB = pixB - hB*WD;
    short8 BfB[9];
    {
      short8 th = *(const short8*)(hqt + (size_t)pixB*MIDM + q*8);
      float hv[8];
#pragma unroll
      for (int j = 0; j < 8; j++) hv[j] = b2f((unsigned short)th[j]);
      const unsigned short* gkb = gkt + ((size_t)hB*PW + wB)*MIDM + q*8;
#pragma unroll
      for (int p = 0; p < 9; p++) {
        short8 tg = *(const short8*)(gkb + (size_t)((p/3)*PW + (p - (p/3)*3))*MIDM);
#pragma unroll
        for (int j = 0; j < 8; j++)
          BfB[p][j] = (short)f2b(fmaxf(sc[j]*(hv[j] + b2f((unsigned short)tg[j])) + ba[j], 0.f));
      }
    }
    int ppl = (hB+1)*PW + (wB+1) - wstart;
    float acc[4] = {0.f, 0.f, 0.f, 0.f};
#pragma unroll
    for (int p = 0; p < 9; p++) {
      int lp = ppl + doff[p];
      const unsigned short* vrow = &tileV[lp*VST2];
#pragma unroll
      for (int ot = 0; ot < 4; ot++) {
        f32x4 c = {0.f, 0.f, 0.f, 0.f};
        c = mfma16(A[ot], BfB[p], c);
        ushort4 vv = *(const ushort4*)(vrow + ot*16 + q*4);
        acc[ot] += (c[0] + Qv[ot][0])*b2f(vv.x) + (c[1] + Qv[ot][1])*b2f(vv.y)
                 + (c[2] + Qv[ot][2])*b2f(vv.z) + (c[3] + Qv[ot][3])*b2f(vv.w);
      }
    }
#pragma unroll
    for (int ot = 0; ot < 4; ot++) {
      int co = by*16 + ot*4 + q;
      size_t oidx = ((size_t)b*128 + co)*HWP + pixB;
      if (isbf) __builtin_nontemporal_store(f2b(acc[ot]), (unsigned short*)outp + oidx);
      else      __builtin_nontemporal_store(acc[ot], (float*)outp + oidx);
    }
  }
}

extern "C" void kernel_launch(void* const* d_in, const int* in_sizes, int n_in,
                              void* d_out, int out_size, void* d_ws, size_t ws_size,
                              hipStream_t stream) {
  float* ws = (float*)d_ws;
  hipLaunchKernelGGL(k_prep, dim3(420), dim3(256), 0, stream,
                     d_in[0], d_in[1], d_in[2], d_in[3], d_in[4], d_in[5],
                     d_in[6], d_in[7], d_in[8], d_in[9], d_in[10], d_in[11],
                     d_in[12], d_in[13], d_in[14], d_in[15], d_in[16],
                     d_in[17], d_in[18], d_in[19], d_in[20], ws);
  hipLaunchKernelGGL(k_mid,  dim3(196),      dim3(256), 0, stream, ws);
  hipLaunchKernelGGL(k_gramh,dim3(32, 4),    dim3(256), 0, stream, ws);
  hipLaunchKernelGGL(k_stats,dim3(4),        dim3(512), 0, stream, ws);
  hipLaunchKernelGGL(k_out,  dim3(25, 8, 4), dim3(256), 0, stream, ws, d_out);
}

// Round 9
// 195.434 us; speedup vs baseline: 1.2998x; 1.2998x over previous
//
#include <hip/hip_runtime.h>
#include <hip/hip_bf16.h>

typedef __hip_bfloat16 bf16;
typedef __attribute__((ext_vector_type(8))) short short8;   // 8 bf16 = 4 VGPR
typedef __attribute__((ext_vector_type(4))) float f32x4;

#define HWP 3136
#define WD 56
#define PW 58          // padded width (1-px zero border)
#define PADP 3364      // 58*58
#define CC 128
#define MIDM 32
#define OGN 512
#define NB 4

// workspace offsets in FLOAT units (all multiples of 4 -> 16B aligned)
enum : int {
  OFF_FLAG = 0,                          // [4]
  OFF_W2F  = 4,                          // fp32 [o][m] 512x32
  OFF_SC2  = OFF_W2F + OGN*MIDM,         // [32]
  OFF_SH2  = OFF_SC2 + MIDM,             // [32]
  OFF_B1F  = OFF_SH2 + MIDM,             // [32]
  OFF_B2F  = OFF_B1F + MIDM,             // [512]
  OFF_GNG  = OFF_B2F + OGN,              // [512]
  OFF_GNB  = OFF_GNG + OGN,              // [512]
  OFF_GPART= OFF_GNB + OGN,              // fp32 [b][128][1056] Gram+S1 partials
  OFF_PQ   = OFF_GPART + NB*128*1056,    // float2 [b][512]
  OFF_SS1  = OFF_PQ + NB*OGN*2,          // float2 [128]
  OFF_SSV  = OFF_SS1 + CC*2,             // float2 [512]
  OFF_WKB  = OFF_SSV + OGN*2,            // bf16 [d][c] 128x128
  OFF_WVB  = OFF_WKB + CC*CC/2,          // bf16 [o][c] 512x128
  OFF_W1AB = OFF_WVB + OGN*CC/2,         // bf16 [m][c] 32x128
  OFF_W1BB = OFF_W1AB + MIDM*CC/2,       // bf16 [m][c] 32x128
  OFF_HQT  = OFF_W1BB + MIDM*CC/2,       // bf16 [b][pix][m] (unpadded)
  OFF_GKT  = OFF_HQT + NB*HWP*MIDM/2,    // bf16 [b][pp58][m] PADDED, zero border
  OFF_VT   = OFF_GKT + NB*PADP*MIDM/2,   // bf16 [b][pp58][o] PADDED, zero border
  OFF_R1   = OFF_VT + NB*PADP*OGN/2,     // union region
  OFF_XT   = OFF_R1,                     // bf16 [b][pix][c]   (phase 1: prep->mid)
  OFF_AB   = OFF_R1,                     // bf16 [b][o][m]     (phase 2: stats->out)
  WS_TOTAL = OFF_R1 + NB*9*HWP*MIDM/2
};

__device__ __forceinline__ float b2f(unsigned short u) {
  bf16 h; *(unsigned short*)&h = u; return __bfloat162float(h);
}
__device__ __forceinline__ unsigned short f2b(float f) {
  bf16 h = __float2bfloat16(f); return *(unsigned short*)&h;
}
__device__ __forceinline__ float ldmix(const void* p, size_t i, bool isbf) {
  return isbf ? __bfloat162float(((const bf16*)p)[i]) : ((const float*)p)[i];
}
__device__ __forceinline__ f32x4 mfma16(short8 a, short8 b, f32x4 c) {
  return __builtin_amdgcn_mfma_f32_16x16x32_bf16(a, b, c, 0, 0, 0);
}
__device__ __forceinline__ bool detect_bf(const unsigned short* xr) {
  int cnt = 0;
#pragma unroll
  for (int i = 0; i < 32; i++) {
    short8 v = *(const short8*)(xr + i*8);
#pragma unroll
    for (int j = 0; j < 8; j++) {
      int e = (((unsigned short)v[j]) >> 7) & 0xFF;
      cnt += (e >= 141) ? 1 : 0;
    }
  }
  return cnt < 8;
}

// ---- L1: detect + params + x->xt transpose (blocks 0..391) + border zero ----
__global__ __launch_bounds__(256) void k_prep(
    const void* __restrict__ x,  const void* __restrict__ Wk,
    const void* __restrict__ bn1_g, const void* __restrict__ bn1_b,
    const void* __restrict__ bn1_m, const void* __restrict__ bn1_v,
    const void* __restrict__ W1, const void* __restrict__ b1,
    const void* __restrict__ bn2_g, const void* __restrict__ bn2_b,
    const void* __restrict__ bn2_m, const void* __restrict__ bn2_v,
    const void* __restrict__ W2, const void* __restrict__ b2,
    const void* __restrict__ gn_g, const void* __restrict__ gn_b,
    const void* __restrict__ Wv,
    const void* __restrict__ bnv_g, const void* __restrict__ bnv_b,
    const void* __restrict__ bnv_m, const void* __restrict__ bnv_v,
    float* __restrict__ ws) {
  __shared__ unsigned short tile[32*130];
  const bool isbf = detect_bf((const unsigned short*)x);
  int blk = blockIdx.x, tid = threadIdx.x;
  if (blk == 0 && tid == 0) ws[OFF_FLAG] = isbf ? 1.f : 0.f;
  int gid = blk*256 + tid, gstride = gridDim.x*256;
  unsigned short* wkb = (unsigned short*)(ws + OFF_WKB);
  unsigned short* wvb = (unsigned short*)(ws + OFF_WVB);
  unsigned short* w1ab = (unsigned short*)(ws + OFF_W1AB);
  unsigned short* w1bb = (unsigned short*)(ws + OFF_W1BB);
  float2* ss1 = (float2*)(ws + OFF_SS1);
  float2* ssv = (float2*)(ws + OFF_SSV);
  for (int i = gid; i < CC*CC; i += gstride) wkb[i] = f2b(ldmix(Wk, i, isbf));
  for (int i = gid; i < OGN*CC; i += gstride) wvb[i] = f2b(ldmix(Wv, i, isbf));
  for (int i = gid; i < MIDM*CC; i += gstride) {
    int m = i / CC, c = i % CC;
    w1ab[i] = f2b(ldmix(W1, (size_t)m*(2*CC) + c, isbf));
    w1bb[i] = f2b(ldmix(W1, (size_t)m*(2*CC) + CC + c, isbf));
  }
  for (int i = gid; i < OGN*MIDM; i += gstride) ws[OFF_W2F + i] = ldmix(W2, i, isbf);
  for (int i = gid; i < CC; i += gstride) {
    float s = ldmix(bn1_g, i, isbf) / sqrtf(ldmix(bn1_v, i, isbf) + 1e-5f);
    ss1[i] = make_float2(s, ldmix(bn1_b, i, isbf) - ldmix(bn1_m, i, isbf) * s);
  }
  for (int i = gid; i < MIDM; i += gstride) {
    float s = ldmix(bn2_g, i, isbf) / sqrtf(ldmix(bn2_v, i, isbf) + 1e-5f);
    ws[OFF_SC2 + i] = s;
    ws[OFF_SH2 + i] = ldmix(bn2_b, i, isbf) - ldmix(bn2_m, i, isbf)*s;
    ws[OFF_B1F + i] = ldmix(b1, i, isbf);
  }
  for (int i = gid; i < OGN; i += gstride) {
    float s = ldmix(bnv_g, i, isbf) / sqrtf(ldmix(bnv_v, i, isbf) + 1e-5f);
    ssv[i] = make_float2(s, ldmix(bnv_b, i, isbf) - ldmix(bnv_m, i, isbf) * s);
    ws[OFF_B2F + i] = ldmix(b2, i, isbf);
    ws[OFF_GNG + i] = ldmix(gn_g, i, isbf);
    ws[OFF_GNB + i] = ldmix(gn_b, i, isbf);
  }
  if (blk < 392) {
    int b = blk / 98, pix0 = (blk % 98)*32;
#pragma unroll
    for (int k = 0; k < 16; k++) {
      int idx = tid + k*256;
      int c = idx >> 5, pl = idx & 31;
      tile[pl*130 + c] = f2b(ldmix(x, ((size_t)b*CC + c)*HWP + pix0 + pl, isbf));
    }
    __syncthreads();
    unsigned short* xt = (unsigned short*)(ws + OFF_XT);
#pragma unroll
    for (int k = 0; k < 16; k++) {
      int idx = tid + k*256;
      int c = idx & 127, pl = idx >> 7;
      xt[((size_t)b*HWP + pix0 + pl)*CC + c] = tile[pl*130 + c];
    }
  } else {
    // zero: vt border (912 pps x 64 o-chunks) + whole gkt_pad
    const int NV = 912*64, NG = NB*PADP*4;
    const short8 z = {0,0,0,0,0,0,0,0};
    unsigned short* vt = (unsigned short*)(ws + OFF_VT);
    unsigned short* gk = (unsigned short*)(ws + OFF_GKT);
    for (int u = (blk-392)*256 + tid; u < NV + NG; u += 28*256) {
      if (u < NV) {
        int bpp = u >> 6, och = u & 63;
        int b = bpp / 228, j = bpp - b*228;
        int pp;
        if (j < 58)       pp = j;
        else if (j < 116) pp = 57*PW + (j - 58);
        else if (j < 172) pp = (j - 116 + 1)*PW;
        else              pp = (j - 172 + 1)*PW + 57;
        *(short8*)(vt + ((size_t)b*PADP + pp)*OGN + och*8) = z;
      } else {
        int u2 = u - NV;
        int b = u2 / (PADP*4), rem = u2 - b*(PADP*4);
        int pp = rem >> 2, mch = rem & 3;
        *(short8*)(gk + ((size_t)b*PADP + pp)*MIDM + mch*8) = z;
      }
    }
  }
}

// ---- L2: keq (blocks 0..195) | v (blocks 196..391): v-block computes ALL
//      512 o for its 64-px strip (xt read once, wvb reused 4x vs r6). ----
__global__ __launch_bounds__(256, 4) void k_mid(float* __restrict__ ws) {
  __shared__ unsigned short keL[4][16][136];
  int bid = blockIdx.x, tid = threadIdx.x;
  int w = tid >> 6, lane = tid & 63, q = lane >> 4, l16 = lane & 15;
  if (bid < 196) {
    int b = bid / 49, bx = bid - (bid/49)*49;
    int pix = bx*64 + w*16 + l16;
    const unsigned short* xt = (const unsigned short*)(ws + OFF_XT) + ((size_t)b*HWP + pix)*CC;
    short8 Bx[4];
#pragma unroll
    for (int kk = 0; kk < 4; kk++) Bx[kk] = *(const short8*)(xt + kk*32 + q*8);
    const unsigned short* wkb = (const unsigned short*)(ws + OFF_WKB);
    const float2* ss = (const float2*)(ws + OFF_SS1);
#pragma unroll
    for (int ot = 0; ot < 8; ot++) {
      int drow = ot*16 + l16;
      f32x4 c = {0.f, 0.f, 0.f, 0.f};
#pragma unroll
      for (int kk = 0; kk < 4; kk++)
        c = mfma16(*(const short8*)(wkb + (size_t)drow*CC + kk*32 + q*8), Bx[kk], c);
      int d0 = ot*16 + q*4;
      ushort4 st;
      { float2 s = ss[d0+0]; st.x = f2b(fmaxf(s.x*c[0] + s.y, 0.f)); }
      { float2 s = ss[d0+1]; st.y = f2b(fmaxf(s.x*c[1] + s.y, 0.f)); }
      { float2 s = ss[d0+2]; st.z = f2b(fmaxf(s.x*c[2] + s.y, 0.f)); }
      { float2 s = ss[d0+3]; st.w = f2b(fmaxf(s.x*c[3] + s.y, 0.f)); }
      *(ushort4*)&keL[w][l16][d0] = st;
    }
    __syncthreads();
    short8 Bk[4];
#pragma unroll
    for (int kk = 0; kk < 4; kk++) Bk[kk] = *(const short8*)&keL[w][l16][kk*32 + q*8];
    const unsigned short* w1a = (const unsigned short*)(ws + OFF_W1AB);
    const unsigned short* w1b = (const unsigned short*)(ws + OFF_W1BB);
    int h0 = pix / WD, w0 = pix - h0*WD;
    int pp = (h0+1)*PW + (w0+1);
    unsigned short* hqt = (unsigned short*)(ws + OFF_HQT) + ((size_t)b*HWP + pix)*MIDM;
    unsigned short* gkt = (unsigned short*)(ws + OFF_GKT) + ((size_t)b*PADP + pp)*MIDM;
#pragma unroll
    for (int mt = 0; mt < 2; mt++) {
      int mrow = mt*16 + l16;
      f32x4 ch = {0.f,0.f,0.f,0.f}, cg = {0.f,0.f,0.f,0.f};
#pragma unroll
      for (int kk = 0; kk < 4; kk++) {
        ch = mfma16(*(const short8*)(w1a + (size_t)mrow*CC + kk*32 + q*8), Bx[kk], ch);
        cg = mfma16(*(const short8*)(w1b + (size_t)mrow*CC + kk*32 + q*8), Bk[kk], cg);
      }
      int m0 = mt*16 + q*4;
      ushort4 sh, sg;
      sh.x = f2b(ch[0]); sh.y = f2b(ch[1]); sh.z = f2b(ch[2]); sh.w = f2b(ch[3]);
      sg.x = f2b(cg[0]); sg.y = f2b(cg[1]); sg.z = f2b(cg[2]); sg.w = f2b(cg[3]);
      *(ushort4*)(hqt + m0) = sh;
      *(ushort4*)(gkt + m0) = sg;
    }
  } else {
    int vid = bid - 196;
    int bx = vid % 49, b = vid / 49;
    int pix = bx*64 + w*16 + l16;
    int h0 = pix / WD, w0 = pix - h0*WD;
    int pp = (h0+1)*PW + (w0+1);
    const unsigned short* xt = (const unsigned short*)(ws + OFF_XT) + ((size_t)b*HWP + pix)*CC;
    short8 B[4];
#pragma unroll
    for (int kk = 0; kk < 4; kk++) B[kk] = *(const short8*)(xt + kk*32 + q*8);
    const unsigned short* wvb = (const unsigned short*)(ws + OFF_WVB);
    const float2* ss = (const float2*)(ws + OFF_SSV);
    unsigned short* vt = (unsigned short*)(ws + OFF_VT) + ((size_t)b*PADP + pp)*OGN;
#pragma unroll
    for (int ot = 0; ot < 32; ot++) {
      int orow = ot*16 + l16;
      f32x4 c = {0.f, 0.f, 0.f, 0.f};
#pragma unroll
      for (int kk = 0; kk < 4; kk++)
        c = mfma16(*(const short8*)(wvb + (size_t)orow*CC + kk*32 + q*8), B[kk], c);
      int o0 = ot*16 + q*4;
      ushort4 st;
      { float2 s = ss[o0+0]; st.x = f2b(s.x*c[0] + s.y); }
      { float2 s = ss[o0+1]; st.y = f2b(s.x*c[1] + s.y); }
      { float2 s = ss[o0+2]; st.z = f2b(s.x*c[2] + s.y); }
      { float2 s = ss[o0+3]; st.w = f2b(s.x*c[3] + s.y); }
      *(ushort4*)(vt + o0) = st;
    }
  }
}

// ---- L3: Gram/S1 partials only (k_out recomputes hs). grid (32,4). ----
__global__ __launch_bounds__(256) void k_gramh(float* __restrict__ ws) {
  __shared__ unsigned short tileT[32][264];
  int b = blockIdx.y, bk = blockIdx.x;
  int tid = threadIdx.x;
  int w = tid >> 6, lane = tid & 63, q = lane >> 4, l16 = lane & 15;
  const int base = bk * 882;                 // 28224 / 32
  const unsigned short* hqt = (const unsigned short*)(ws + OFF_HQT) + (size_t)b*HWP*MIDM;
  const unsigned short* gkp = (const unsigned short*)(ws + OFF_GKT) + (size_t)b*PADP*MIDM;
  float sc2[MIDM], bas0[MIDM];
#pragma unroll
  for (int m = 0; m < MIDM; m++) {
    sc2[m] = ws[OFF_SC2 + m];
    bas0[m] = sc2[m]*ws[OFF_B1F + m] + ws[OFF_SH2 + m];
  }
  f32x4 gLL={0,0,0,0}, gLH={0,0,0,0}, gHH={0,0,0,0}, sL={0,0,0,0}, sH={0,0,0,0};
  short8 ones;
#pragma unroll
  for (int j = 0; j < 8; j++) ones[j] = (short)0x3F80;
  for (int t = 0; t < 4; t++) {
    int r = t*256 + tid;
    bool valid = r < 882;
    int R = valid ? (base + r) : 0;
    int p = R / HWP, pix = R - p*HWP;
    int h0 = pix / WD, w0 = pix - h0*WD;
    int npp = (h0 + p/3)*PW + (w0 + p - (p/3)*3);
    const unsigned short* hq = hqt + (size_t)pix*MIDM;
    const unsigned short* gk = gkp + (size_t)npp*MIDM;
#pragma unroll
    for (int ch = 0; ch < 4; ch++) {
      short8 th = *(const short8*)(hq + ch*8);
      short8 tg = *(const short8*)(gk + ch*8);
      short8 o;
#pragma unroll
      for (int j = 0; j < 8; j++) {
        int m = ch*8 + j;
        float hv = b2f((unsigned short)th[j]) + b2f((unsigned short)tg[j]);
        float v = fmaxf(sc2[m]*hv + bas0[m], 0.f);
        o[j] = valid ? (short)f2b(v) : (short)0;
      }
#pragma unroll
      for (int j = 0; j < 8; j++) tileT[ch*8 + j][tid] = (unsigned short)o[j];
    }
    __syncthreads();
#pragma unroll
    for (int cc = 0; cc < 2; cc++) {
      int c = w*2 + cc;
      short8 alo = *(const short8*)&tileT[l16][c*32 + q*8];
      short8 ahi = *(const short8*)&tileT[l16+16][c*32 + q*8];
      gLL = mfma16(alo, alo, gLL);
      gLH = mfma16(alo, ahi, gLH);
      gHH = mfma16(ahi, ahi, gHH);
      sL = mfma16(alo, ones, sL);
      sH = mfma16(ahi, ones, sH);
    }
    __syncthreads();
  }
  float* blob = ws + OFF_GPART + ((size_t)((b*32 + bk)*4 + w))*1056;
#pragma unroll
  for (int r = 0; r < 4; r++) {
    int row = q*4 + r;
    blob[row*32 + l16]             = gLL[r];
    blob[row*32 + 16 + l16]        = gLH[r];
    blob[(16 + l16)*32 + row]      = gLH[r];   // HL = LH^T
    blob[(16 + row)*32 + 16 + l16] = gHH[r];
  }
  if (l16 == 0) {
#pragma unroll
    for (int r = 0; r < 4; r++) {
      blob[1024 + q*4 + r]      = sL[r];
      blob[1024 + 16 + q*4 + r] = sH[r];
    }
  }
}

// ---- L4: GN stats -> PQ + precompute AB = f2b(alpha*W2). grid (4) x 512 ----
__global__ __launch_bounds__(512) void k_stats(float* __restrict__ ws) {
  __shared__ float Gs[MIDM*MIDM], S1s[MIDM], saS[OGN], sqS[OGN], muS[128], invS[128];
  int b = blockIdx.x, o = threadIdx.x;
  for (int e = o; e < 1056; e += 512) {
    float s = 0.f;
    const float* pb = ws + OFF_GPART + (size_t)b*128*1056 + e;
    for (int p = 0; p < 128; p++) s += pb[(size_t)p*1056];
    if (e < 1024) Gs[e] = s; else S1s[e - 1024] = s;
  }
  __syncthreads();
  float w2[MIDM];
#pragma unroll
  for (int m = 0; m < MIDM; m++) w2[m] = ws[OFF_W2F + o*MIDM + m];
  float dotS = 0.f;
#pragma unroll
  for (int m = 0; m < MIDM; m++) dotS += w2[m] * S1s[m];
  float quad = 0.f;
  for (int a = 0; a < MIDM; a++) {
    float t = 0.f;
#pragma unroll
    for (int c = 0; c < MIDM; c++) t += Gs[a*MIDM + c] * w2[c];
    quad += w2[a] * t;
  }
  float b2o = ws[OFF_B2F + o];
  const float M = 9.f * HWP;
  saS[o] = dotS + b2o * M;
  sqS[o] = quad + 2.f*b2o*dotS + b2o*b2o*M;
  __syncthreads();
  if (o < 128) {
    float sa = saS[4*o] + saS[4*o+1] + saS[4*o+2] + saS[4*o+3];
    float sq = sqS[4*o] + sqS[4*o+1] + sqS[4*o+2] + sqS[4*o+3];
    const float invN = 1.f / (4.f * M);
    float mu = sa * invN;
    float var = sq * invN - mu*mu;
    muS[o] = mu;
    invS[o] = 1.f / sqrtf(var + 1e-5f);
  }
  __syncthreads();
  int co = o >> 2;
  float alpha = ws[OFF_GNG + o] * invS[co];
  ((float2*)(ws + OFF_PQ))[b*OGN + o] =
      make_float2(alpha, alpha*b2o + ws[OFF_GNB + o] - muS[co]*alpha);
  unsigned short* dst = (unsigned short*)(ws + OFF_AB) + ((size_t)b*OGN + o)*MIDM;
#pragma unroll
  for (int m = 0; m < MIDM; m += 4) {
    ushort4 t;
    t.x = f2b(alpha*w2[m+0]); t.y = f2b(alpha*w2[m+1]);
    t.z = f2b(alpha*w2[m+2]); t.w = f2b(alpha*w2[m+3]);
    *(ushort4*)(dst + m) = t;
  }
}

// ---- L5: epilogue (r6-exact). 128-px double-strip x 128-o by-PAIR window;
//      Bf recomputed once per strip, shared by both 64-o tiles.
//      grid (25,4,4), 256 thr, 2 blocks/CU, VST=136. ----
#define VST 136   // u16 row stride for 128-o window
__global__ __launch_bounds__(256, 2) void k_out(const float* __restrict__ ws,
                                                void* __restrict__ outp) {
  __shared__ unsigned short tileV[256*VST];    // 69.6 KB
  int b = blockIdx.z, bp = blockIdx.y;         // bp in [0,4): o-base bp*128
  int bx = blockIdx.x;                         // 0..24: 128-px double strip
  int tid = threadIdx.x;
  int w = tid >> 6, lane = tid & 63, q = lane >> 4, l16 = lane & 15;
  int pix0 = bx*128;
  int h00 = pix0 / WD, w00 = pix0 - h00*WD;
  int wstart = (h00+1)*PW + (w00+1) - (PW+1);
  const bool hasB = (bx < 24);
  int pixA = pix0 + w*16 + l16;
  float sc[8], ba[8];
#pragma unroll
  for (int j = 0; j < 8; j++) {
    int m = q*8 + j;
    sc[j] = ws[OFF_SC2 + m];
    ba[j] = sc[j]*ws[OFF_B1F + m] + ws[OFF_SH2 + m];
  }
  const unsigned short* hqt = (const unsigned short*)(ws + OFF_HQT) + (size_t)b*HWP*MIDM;
  const unsigned short* gkt = (const unsigned short*)(ws + OFF_GKT) + (size_t)b*PADP*MIDM;
  int hA = pixA / WD, wA = pixA - hA*WD;
  short8 BfA[9];
  {
    short8 th = *(const short8*)(hqt + (size_t)pixA*MIDM + q*8);
    float hv[8];
#pragma unroll
    for (int j = 0; j < 8; j++) hv[j] = b2f((unsigned short)th[j]);
    const unsigned short* gkb = gkt + ((size_t)hA*PW + wA)*MIDM + q*8;
#pragma unroll
    for (int p = 0; p < 9; p++) {
      short8 tg = *(const short8*)(gkb + (size_t)((p/3)*PW + (p - (p/3)*3))*MIDM);
#pragma unroll
      for (int j = 0; j < 8; j++)
        BfA[p][j] = (short)f2b(fmaxf(sc[j]*(hv[j] + b2f((unsigned short)tg[j])) + ba[j], 0.f));
    }
  }
  // stage vt window: 256 pps x 128 o, as 4096 short8 (16 B) chunks
  const unsigned short* vsrc = (const unsigned short*)(ws + OFF_VT)
      + (size_t)b*PADP*OGN + (size_t)bp*128;
#pragma unroll
  for (int i = 0; i < 16; i++) {
    int u = i*256 + tid;                  // 0..4095
    int wp = u >> 4, col = (u & 15)*8;    // 256 rows x 16 chunks x 8 u16
    *(short8*)&tileV[wp*VST + col] =
        *(const short8*)(vsrc + (size_t)(wstart + wp)*OGN + col);
  }
  const bool isbf = ws[OFF_FLAG] > 0.5f;
  const float2* pq = (const float2*)(ws + OFF_PQ) + b*OGN;
  const unsigned short* ABb = (const unsigned short*)(ws + OFF_AB)
      + ((size_t)b*OGN + bp*128)*MIDM;
  const int doff[9] = {-PW-1, -PW, -PW+1, -1, 0, 1, PW-1, PW, PW+1};
  int pplA = (hA+1)*PW + (wA+1) - wstart;
  __syncthreads();
  for (int byv = 0; byv < 2; ++byv) {
    short8 A[4];
    f32x4 Qv[4];
#pragma unroll
    for (int ot = 0; ot < 4; ot++) {
      A[ot] = *(const short8*)(ABb + (size_t)(byv*64 + ot*16 + l16)*MIDM + q*8);
      int o0 = bp*128 + byv*64 + ot*16 + q*4;
      f32x4 qv = { pq[o0+0].y, pq[o0+1].y, pq[o0+2].y, pq[o0+3].y };
      Qv[ot] = qv;
    }
    // strip A
    {
      float acc[4] = {0.f, 0.f, 0.f, 0.f};
#pragma unroll
      for (int p = 0; p < 9; p++) {
        int lp = pplA + doff[p];
        const unsigned short* vrow = &tileV[lp*VST + byv*64];
#pragma unroll
        for (int ot = 0; ot < 4; ot++) {
          f32x4 c = {0.f, 0.f, 0.f, 0.f};
          c = mfma16(A[ot], BfA[p], c);
          ushort4 vv = *(const ushort4*)(vrow + ot*16 + q*4);
          acc[ot] += (c[0] + Qv[ot][0])*b2f(vv.x) + (c[1] + Qv[ot][1])*b2f(vv.y)
                   + (c[2] + Qv[ot][2])*b2f(vv.z) + (c[3] + Qv[ot][3])*b2f(vv.w);
        }
      }
#pragma unroll
      for (int ot = 0; ot < 4; ot++) {
        int co = bp*32 + byv*16 + ot*4 + q;
        size_t oidx = ((size_t)b*128 + co)*HWP + pixA;
        if (isbf) __builtin_nontemporal_store(f2b(acc[ot]), (unsigned short*)outp + oidx);
        else      __builtin_nontemporal_store(acc[ot], (float*)outp + oidx);
      }
    }
    // strip B
    if (hasB) {
      int pixB = pixA + 64;
      int hB = pixB / WD, wB = pixB - hB*WD;
      short8 BfB[9];
      {
        short8 th = *(const short8*)(hqt + (size_t)pixB*MIDM + q*8);
        float hv[8];
#pragma unroll
        for (int j = 0; j < 8; j++) hv[j] = b2f((unsigned short)th[j]);
        const unsigned short* gkb = gkt + ((size_t)hB*PW + wB)*MIDM + q*8;
#pragma unroll
        for (int p = 0; p < 9; p++) {
          short8 tg = *(const short8*)(gkb + (size_t)((p/3)*PW + (p - (p/3)*3))*MIDM);
#pragma unroll
          for (int j = 0; j < 8; j++)
            BfB[p][j] = (short)f2b(fmaxf(sc[j]*(hv[j] + b2f((unsigned short)tg[j])) + ba[j], 0.f));
        }
      }
      int ppl = (hB+1)*PW + (wB+1) - wstart;
      float acc[4] = {0.f, 0.f, 0.f, 0.f};
#pragma unroll
      for (int p = 0; p < 9; p++) {
        int lp = ppl + doff[p];
        const unsigned short* vrow = &tileV[lp*VST + byv*64];
#pragma unroll
        for (int ot = 0; ot < 4; ot++) {
          f32x4 c = {0.f, 0.f, 0.f, 0.f};
          c = mfma16(A[ot], BfB[p], c);
          ushort4 vv = *(const ushort4*)(vrow + ot*16 + q*4);
          acc[ot] += (c[0] + Qv[ot][0])*b2f(vv.x) + (c[1] + Qv[ot][1])*b2f(vv.y)
                   + (c[2] + Qv[ot][2])*b2f(vv.z) + (c[3] + Qv[ot][3])*b2f(vv.w);
        }
      }
#pragma unroll
      for (int ot = 0; ot < 4; ot++) {
        int co = bp*32 + byv*16 + ot*4 + q;
        size_t oidx = ((size_t)b*128 + co)*HWP + pixB;
        if (isbf) __builtin_nontemporal_store(f2b(acc[ot]), (unsigned short*)outp + oidx);
        else      __builtin_nontemporal_store(acc[ot], (float*)outp + oidx);
      }
    }
  }
}

extern "C" void kernel_launch(void* const* d_in, const int* in_sizes, int n_in,
                              void* d_out, int out_size, void* d_ws, size_t ws_size,
                              hipStream_t stream) {
  float* ws = (float*)d_ws;
  hipLaunchKernelGGL(k_prep, dim3(420), dim3(256), 0, stream,
                     d_in[0], d_in[1], d_in[2], d_in[3], d_in[4], d_in[5],
                     d_in[6], d_in[7], d_in[8], d_in[9], d_in[10], d_in[11],
                     d_in[12], d_in[13], d_in[14], d_in[15], d_in[16],
                     d_in[17], d_in[18], d_in[19], d_in[20], ws);
  hipLaunchKernelGGL(k_mid,  dim3(392),      dim3(256), 0, stream, ws);
  hipLaunchKernelGGL(k_gramh,dim3(32, 4),    dim3(256), 0, stream, ws);
  hipLaunchKernelGGL(k_stats,dim3(4),        dim3(512), 0, stream, ws);
  hipLaunchKernelGGL(k_out,  dim3(25, 4, 4), dim3(256), 0, stream, ws, d_out);
}

// Round 10
// 192.546 us; speedup vs baseline: 1.3193x; 1.0150x over previous
//
#include <hip/hip_runtime.h>
#include <hip/hip_bf16.h>

typedef __hip_bfloat16 bf16;
typedef __attribute__((ext_vector_type(8))) short short8;   // 8 bf16 = 4 VGPR
typedef __attribute__((ext_vector_type(4))) float f32x4;

#define HWP 3136
#define WD 56
#define PW 58          // padded width (1-px zero border)
#define PADP 3364      // 58*58
#define CC 128
#define MIDM 32
#define OGN 512
#define NB 4

// workspace offsets in FLOAT units (all multiples of 4 -> 16B aligned)
enum : int {
  OFF_FLAG = 0,                          // [4]
  OFF_W2F  = 4,                          // fp32 [o][m] 512x32
  OFF_SC2  = OFF_W2F + OGN*MIDM,         // [32]
  OFF_SH2  = OFF_SC2 + MIDM,             // [32]
  OFF_B1F  = OFF_SH2 + MIDM,             // [32]
  OFF_B2F  = OFF_B1F + MIDM,             // [512]
  OFF_GNG  = OFF_B2F + OGN,              // [512]
  OFF_GNB  = OFF_GNG + OGN,              // [512]
  OFF_GPART= OFF_GNB + OGN,              // fp32 [b][128][1056] Gram+S1 partials
  OFF_PQ   = OFF_GPART + NB*128*1056,    // float2 [b][512]
  OFF_SS1  = OFF_PQ + NB*OGN*2,          // float2 [128]
  OFF_SSV  = OFF_SS1 + CC*2,             // float2 [512]
  OFF_WKB  = OFF_SSV + OGN*2,            // bf16 [d][c] 128x128
  OFF_WVB  = OFF_WKB + CC*CC/2,          // bf16 [o][c] 512x128
  OFF_W1AB = OFF_WVB + OGN*CC/2,         // bf16 [m][c] 32x128
  OFF_W1BB = OFF_W1AB + MIDM*CC/2,       // bf16 [m][c] 32x128
  OFF_HQT  = OFF_W1BB + MIDM*CC/2,       // bf16 [b][pix][m] (unpadded)
  OFF_GKT  = OFF_HQT + NB*HWP*MIDM/2,    // bf16 [b][pp58][m] PADDED, zero border
  OFF_VT   = OFF_GKT + NB*PADP*MIDM/2,   // bf16 [b][pp58][o] PADDED, zero border
  OFF_R1   = OFF_VT + NB*PADP*OGN/2,     // union region
  OFF_XT   = OFF_R1,                     // bf16 [b][pix][c]   (phase 1: prep->mid)
  OFF_AB   = OFF_R1,                     // bf16 [b][o][m]     (phase 2: stats->out)
  WS_TOTAL = OFF_R1 + NB*9*HWP*MIDM/2
};

__device__ __forceinline__ float b2f(unsigned short u) {
  bf16 h; *(unsigned short*)&h = u; return __bfloat162float(h);
}
__device__ __forceinline__ unsigned short f2b(float f) {
  bf16 h = __float2bfloat16(f); return *(unsigned short*)&h;
}
__device__ __forceinline__ float ldmix(const void* p, size_t i, bool isbf) {
  return isbf ? __bfloat162float(((const bf16*)p)[i]) : ((const float*)p)[i];
}
__device__ __forceinline__ f32x4 mfma16(short8 a, short8 b, f32x4 c) {
  return __builtin_amdgcn_mfma_f32_16x16x32_bf16(a, b, c, 0, 0, 0);
}
__device__ __forceinline__ bool detect_bf(const unsigned short* xr) {
  int cnt = 0;
#pragma unroll
  for (int i = 0; i < 32; i++) {
    short8 v = *(const short8*)(xr + i*8);
#pragma unroll
    for (int j = 0; j < 8; j++) {
      int e = (((unsigned short)v[j]) >> 7) & 0xFF;
      cnt += (e >= 141) ? 1 : 0;
    }
  }
  return cnt < 8;
}

// ---- L1: detect + params + x->xt transpose (blocks 0..391) + border zero ----
__global__ __launch_bounds__(256) void k_prep(
    const void* __restrict__ x,  const void* __restrict__ Wk,
    const void* __restrict__ bn1_g, const void* __restrict__ bn1_b,
    const void* __restrict__ bn1_m, const void* __restrict__ bn1_v,
    const void* __restrict__ W1, const void* __restrict__ b1,
    const void* __restrict__ bn2_g, const void* __restrict__ bn2_b,
    const void* __restrict__ bn2_m, const void* __restrict__ bn2_v,
    const void* __restrict__ W2, const void* __restrict__ b2,
    const void* __restrict__ gn_g, const void* __restrict__ gn_b,
    const void* __restrict__ Wv,
    const void* __restrict__ bnv_g, const void* __restrict__ bnv_b,
    const void* __restrict__ bnv_m, const void* __restrict__ bnv_v,
    float* __restrict__ ws) {
  __shared__ unsigned short tile[32*130];
  const bool isbf = detect_bf((const unsigned short*)x);
  int blk = blockIdx.x, tid = threadIdx.x;
  if (blk == 0 && tid == 0) ws[OFF_FLAG] = isbf ? 1.f : 0.f;
  int gid = blk*256 + tid, gstride = gridDim.x*256;
  unsigned short* wkb = (unsigned short*)(ws + OFF_WKB);
  unsigned short* wvb = (unsigned short*)(ws + OFF_WVB);
  unsigned short* w1ab = (unsigned short*)(ws + OFF_W1AB);
  unsigned short* w1bb = (unsigned short*)(ws + OFF_W1BB);
  float2* ss1 = (float2*)(ws + OFF_SS1);
  float2* ssv = (float2*)(ws + OFF_SSV);
  for (int i = gid; i < CC*CC; i += gstride) wkb[i] = f2b(ldmix(Wk, i, isbf));
  for (int i = gid; i < OGN*CC; i += gstride) wvb[i] = f2b(ldmix(Wv, i, isbf));
  for (int i = gid; i < MIDM*CC; i += gstride) {
    int m = i / CC, c = i % CC;
    w1ab[i] = f2b(ldmix(W1, (size_t)m*(2*CC) + c, isbf));
    w1bb[i] = f2b(ldmix(W1, (size_t)m*(2*CC) + CC + c, isbf));
  }
  for (int i = gid; i < OGN*MIDM; i += gstride) ws[OFF_W2F + i] = ldmix(W2, i, isbf);
  for (int i = gid; i < CC; i += gstride) {
    float s = ldmix(bn1_g, i, isbf) / sqrtf(ldmix(bn1_v, i, isbf) + 1e-5f);
    ss1[i] = make_float2(s, ldmix(bn1_b, i, isbf) - ldmix(bn1_m, i, isbf) * s);
  }
  for (int i = gid; i < MIDM; i += gstride) {
    float s = ldmix(bn2_g, i, isbf) / sqrtf(ldmix(bn2_v, i, isbf) + 1e-5f);
    ws[OFF_SC2 + i] = s;
    ws[OFF_SH2 + i] = ldmix(bn2_b, i, isbf) - ldmix(bn2_m, i, isbf)*s;
    ws[OFF_B1F + i] = ldmix(b1, i, isbf);
  }
  for (int i = gid; i < OGN; i += gstride) {
    float s = ldmix(bnv_g, i, isbf) / sqrtf(ldmix(bnv_v, i, isbf) + 1e-5f);
    ssv[i] = make_float2(s, ldmix(bnv_b, i, isbf) - ldmix(bnv_m, i, isbf) * s);
    ws[OFF_B2F + i] = ldmix(b2, i, isbf);
    ws[OFF_GNG + i] = ldmix(gn_g, i, isbf);
    ws[OFF_GNB + i] = ldmix(gn_b, i, isbf);
  }
  if (blk < 392) {
    int b = blk / 98, pix0 = (blk % 98)*32;
#pragma unroll
    for (int k = 0; k < 16; k++) {
      int idx = tid + k*256;
      int c = idx >> 5, pl = idx & 31;
      tile[pl*130 + c] = f2b(ldmix(x, ((size_t)b*CC + c)*HWP + pix0 + pl, isbf));
    }
    __syncthreads();
    unsigned short* xt = (unsigned short*)(ws + OFF_XT);
#pragma unroll
    for (int k = 0; k < 16; k++) {
      int idx = tid + k*256;
      int c = idx & 127, pl = idx >> 7;
      xt[((size_t)b*HWP + pix0 + pl)*CC + c] = tile[pl*130 + c];
    }
  } else {
    // zero: vt border (912 pps x 64 o-chunks) + whole gkt_pad
    const int NV = 912*64, NG = NB*PADP*4;
    const short8 z = {0,0,0,0,0,0,0,0};
    unsigned short* vt = (unsigned short*)(ws + OFF_VT);
    unsigned short* gk = (unsigned short*)(ws + OFF_GKT);
    for (int u = (blk-392)*256 + tid; u < NV + NG; u += 28*256) {
      if (u < NV) {
        int bpp = u >> 6, och = u & 63;
        int b = bpp / 228, j = bpp - b*228;
        int pp;
        if (j < 58)       pp = j;
        else if (j < 116) pp = 57*PW + (j - 58);
        else if (j < 172) pp = (j - 116 + 1)*PW;
        else              pp = (j - 172 + 1)*PW + 57;
        *(short8*)(vt + ((size_t)b*PADP + pp)*OGN + och*8) = z;
      } else {
        int u2 = u - NV;
        int b = u2 / (PADP*4), rem = u2 - b*(PADP*4);
        int pp = rem >> 2, mch = rem & 3;
        *(short8*)(gk + ((size_t)b*PADP + pp)*MIDM + mch*8) = z;
      }
    }
  }
}

// ---- L2: keq (blocks 0..195) | v (blocks 196..979)  (r6-exact) ----
__global__ __launch_bounds__(256, 4) void k_mid(float* __restrict__ ws) {
  __shared__ unsigned short keL[4][16][136];
  int bid = blockIdx.x, tid = threadIdx.x;
  int w = tid >> 6, lane = tid & 63, q = lane >> 4, l16 = lane & 15;
  if (bid < 196) {
    int b = bid / 49, bx = bid - (bid/49)*49;
    int pix = bx*64 + w*16 + l16;
    const unsigned short* xt = (const unsigned short*)(ws + OFF_XT) + ((size_t)b*HWP + pix)*CC;
    short8 Bx[4];
#pragma unroll
    for (int kk = 0; kk < 4; kk++) Bx[kk] = *(const short8*)(xt + kk*32 + q*8);
    const unsigned short* wkb = (const unsigned short*)(ws + OFF_WKB);
    const float2* ss = (const float2*)(ws + OFF_SS1);
#pragma unroll
    for (int ot = 0; ot < 8; ot++) {
      int drow = ot*16 + l16;
      f32x4 c = {0.f, 0.f, 0.f, 0.f};
#pragma unroll
      for (int kk = 0; kk < 4; kk++)
        c = mfma16(*(const short8*)(wkb + (size_t)drow*CC + kk*32 + q*8), Bx[kk], c);
      int d0 = ot*16 + q*4;
      ushort4 st;
      { float2 s = ss[d0+0]; st.x = f2b(fmaxf(s.x*c[0] + s.y, 0.f)); }
      { float2 s = ss[d0+1]; st.y = f2b(fmaxf(s.x*c[1] + s.y, 0.f)); }
      { float2 s = ss[d0+2]; st.z = f2b(fmaxf(s.x*c[2] + s.y, 0.f)); }
      { float2 s = ss[d0+3]; st.w = f2b(fmaxf(s.x*c[3] + s.y, 0.f)); }
      *(ushort4*)&keL[w][l16][d0] = st;
    }
    __syncthreads();
    short8 Bk[4];
#pragma unroll
    for (int kk = 0; kk < 4; kk++) Bk[kk] = *(const short8*)&keL[w][l16][kk*32 + q*8];
    const unsigned short* w1a = (const unsigned short*)(ws + OFF_W1AB);
    const unsigned short* w1b = (const unsigned short*)(ws + OFF_W1BB);
    int h0 = pix / WD, w0 = pix - h0*WD;
    int pp = (h0+1)*PW + (w0+1);
    unsigned short* hqt = (unsigned short*)(ws + OFF_HQT) + ((size_t)b*HWP + pix)*MIDM;
    unsigned short* gkt = (unsigned short*)(ws + OFF_GKT) + ((size_t)b*PADP + pp)*MIDM;
#pragma unroll
    for (int mt = 0; mt < 2; mt++) {
      int mrow = mt*16 + l16;
      f32x4 ch = {0.f,0.f,0.f,0.f}, cg = {0.f,0.f,0.f,0.f};
#pragma unroll
      for (int kk = 0; kk < 4; kk++) {
        ch = mfma16(*(const short8*)(w1a + (size_t)mrow*CC + kk*32 + q*8), Bx[kk], ch);
        cg = mfma16(*(const short8*)(w1b + (size_t)mrow*CC + kk*32 + q*8), Bk[kk], cg);
      }
      int m0 = mt*16 + q*4;
      ushort4 sh, sg;
      sh.x = f2b(ch[0]); sh.y = f2b(ch[1]); sh.z = f2b(ch[2]); sh.w = f2b(ch[3]);
      sg.x = f2b(cg[0]); sg.y = f2b(cg[1]); sg.z = f2b(cg[2]); sg.w = f2b(cg[3]);
      *(ushort4*)(hqt + m0) = sh;
      *(ushort4*)(gkt + m0) = sg;
    }
  } else {
    int vid = bid - 196;
    int bx = vid % 49, rest = vid / 49;
    int by = rest & 3, b = rest >> 2;
    int pix = bx*64 + w*16 + l16;
    int h0 = pix / WD, w0 = pix - h0*WD;
    int pp = (h0+1)*PW + (w0+1);
    const unsigned short* xt = (const unsigned short*)(ws + OFF_XT) + ((size_t)b*HWP + pix)*CC;
    short8 B[4];
#pragma unroll
    for (int kk = 0; kk < 4; kk++) B[kk] = *(const short8*)(xt + kk*32 + q*8);
    const unsigned short* wvb = (const unsigned short*)(ws + OFF_WVB);
    const float2* ss = (const float2*)(ws + OFF_SSV);
    unsigned short* vt = (unsigned short*)(ws + OFF_VT) + ((size_t)b*PADP + pp)*OGN;
#pragma unroll
    for (int ot = 0; ot < 8; ot++) {
      int orow = by*128 + ot*16 + l16;
      f32x4 c = {0.f, 0.f, 0.f, 0.f};
#pragma unroll
      for (int kk = 0; kk < 4; kk++)
        c = mfma16(*(const short8*)(wvb + (size_t)orow*CC + kk*32 + q*8), B[kk], c);
      int o0 = by*128 + ot*16 + q*4;
      ushort4 st;
      { float2 s = ss[o0+0]; st.x = f2b(s.x*c[0] + s.y); }
      { float2 s = ss[o0+1]; st.y = f2b(s.x*c[1] + s.y); }
      { float2 s = ss[o0+2]; st.z = f2b(s.x*c[2] + s.y); }
      { float2 s = ss[o0+3]; st.w = f2b(s.x*c[3] + s.y); }
      *(ushort4*)(vt + o0) = st;
    }
  }
}

// ---- L3: Gram/S1 partials only (k_out recomputes hs). grid (32,4). ----
__global__ __launch_bounds__(256) void k_gramh(float* __restrict__ ws) {
  __shared__ unsigned short tileT[32][264];
  int b = blockIdx.y, bk = blockIdx.x;
  int tid = threadIdx.x;
  int w = tid >> 6, lane = tid & 63, q = lane >> 4, l16 = lane & 15;
  const int base = bk * 882;                 // 28224 / 32
  const unsigned short* hqt = (const unsigned short*)(ws + OFF_HQT) + (size_t)b*HWP*MIDM;
  const unsigned short* gkp = (const unsigned short*)(ws + OFF_GKT) + (size_t)b*PADP*MIDM;
  float sc2[MIDM], bas0[MIDM];
#pragma unroll
  for (int m = 0; m < MIDM; m++) {
    sc2[m] = ws[OFF_SC2 + m];
    bas0[m] = sc2[m]*ws[OFF_B1F + m] + ws[OFF_SH2 + m];
  }
  f32x4 gLL={0,0,0,0}, gLH={0,0,0,0}, gHH={0,0,0,0}, sL={0,0,0,0}, sH={0,0,0,0};
  short8 ones;
#pragma unroll
  for (int j = 0; j < 8; j++) ones[j] = (short)0x3F80;
  for (int t = 0; t < 4; t++) {
    int r = t*256 + tid;
    bool valid = r < 882;
    int R = valid ? (base + r) : 0;
    int p = R / HWP, pix = R - p*HWP;
    int h0 = pix / WD, w0 = pix - h0*WD;
    int npp = (h0 + p/3)*PW + (w0 + p - (p/3)*3);
    const unsigned short* hq = hqt + (size_t)pix*MIDM;
    const unsigned short* gk = gkp + (size_t)npp*MIDM;
#pragma unroll
    for (int ch = 0; ch < 4; ch++) {
      short8 th = *(const short8*)(hq + ch*8);
      short8 tg = *(const short8*)(gk + ch*8);
      short8 o;
#pragma unroll
      for (int j = 0; j < 8; j++) {
        int m = ch*8 + j;
        float hv = b2f((unsigned short)th[j]) + b2f((unsigned short)tg[j]);
        float v = fmaxf(sc2[m]*hv + bas0[m], 0.f);
        o[j] = valid ? (short)f2b(v) : (short)0;
      }
#pragma unroll
      for (int j = 0; j < 8; j++) tileT[ch*8 + j][tid] = (unsigned short)o[j];
    }
    __syncthreads();
#pragma unroll
    for (int cc = 0; cc < 2; cc++) {
      int c = w*2 + cc;
      short8 alo = *(const short8*)&tileT[l16][c*32 + q*8];
      short8 ahi = *(const short8*)&tileT[l16+16][c*32 + q*8];
      gLL = mfma16(alo, alo, gLL);
      gLH = mfma16(alo, ahi, gLH);
      gHH = mfma16(ahi, ahi, gHH);
      sL = mfma16(alo, ones, sL);
      sH = mfma16(ahi, ones, sH);
    }
    __syncthreads();
  }
  float* blob = ws + OFF_GPART + ((size_t)((b*32 + bk)*4 + w))*1056;
#pragma unroll
  for (int r = 0; r < 4; r++) {
    int row = q*4 + r;
    blob[row*32 + l16]             = gLL[r];
    blob[row*32 + 16 + l16]        = gLH[r];
    blob[(16 + l16)*32 + row]      = gLH[r];   // HL = LH^T
    blob[(16 + row)*32 + 16 + l16] = gHH[r];
  }
  if (l16 == 0) {
#pragma unroll
    for (int r = 0; r < 4; r++) {
      blob[1024 + q*4 + r]      = sL[r];
      blob[1024 + 16 + q*4 + r] = sH[r];
    }
  }
}

// ---- L4: GN stats -> PQ + precompute AB = f2b(alpha*W2). grid (4) x 512 ----
__global__ __launch_bounds__(512) void k_stats(float* __restrict__ ws) {
  __shared__ float Gs[MIDM*MIDM], S1s[MIDM], saS[OGN], sqS[OGN], muS[128], invS[128];
  int b = blockIdx.x, o = threadIdx.x;
  for (int e = o; e < 1056; e += 512) {
    float s = 0.f;
    const float* pb = ws + OFF_GPART + (size_t)b*128*1056 + e;
    for (int p = 0; p < 128; p++) s += pb[(size_t)p*1056];
    if (e < 1024) Gs[e] = s; else S1s[e - 1024] = s;
  }
  __syncthreads();
  float w2[MIDM];
#pragma unroll
  for (int m = 0; m < MIDM; m++) w2[m] = ws[OFF_W2F + o*MIDM + m];
  float dotS = 0.f;
#pragma unroll
  for (int m = 0; m < MIDM; m++) dotS += w2[m] * S1s[m];
  float quad = 0.f;
  for (int a = 0; a < MIDM; a++) {
    float t = 0.f;
#pragma unroll
    for (int c = 0; c < MIDM; c++) t += Gs[a*MIDM + c] * w2[c];
    quad += w2[a] * t;
  }
  float b2o = ws[OFF_B2F + o];
  const float M = 9.f * HWP;
  saS[o] = dotS + b2o * M;
  sqS[o] = quad + 2.f*b2o*dotS + b2o*b2o*M;
  __syncthreads();
  if (o < 128) {
    float sa = saS[4*o] + saS[4*o+1] + saS[4*o+2] + saS[4*o+3];
    float sq = sqS[4*o] + sqS[4*o+1] + sqS[4*o+2] + sqS[4*o+3];
    const float invN = 1.f / (4.f * M);
    float mu = sa * invN;
    float var = sq * invN - mu*mu;
    muS[o] = mu;
    invS[o] = 1.f / sqrtf(var + 1e-5f);
  }
  __syncthreads();
  int co = o >> 2;
  float alpha = ws[OFF_GNG + o] * invS[co];
  ((float2*)(ws + OFF_PQ))[b*OGN + o] =
      make_float2(alpha, alpha*b2o + ws[OFF_GNB + o] - muS[co]*alpha);
  unsigned short* dst = (unsigned short*)(ws + OFF_AB) + ((size_t)b*OGN + o)*MIDM;
#pragma unroll
  for (int m = 0; m < MIDM; m += 4) {
    ushort4 t;
    t.x = f2b(alpha*w2[m+0]); t.y = f2b(alpha*w2[m+1]);
    t.z = f2b(alpha*w2[m+2]); t.w = f2b(alpha*w2[m+3]);
    *(ushort4*)(dst + m) = t;
  }
}

// ---- L5: epilogue. 64-px strip x 128-o window (Bf shared by both 64-o
//      tiles): LDS 52.2 KB -> 3 blocks/CU (12 waves/CU, +50% TLP vs r6's 2).
//      grid (49,4,4)=784, 256 thr, VST=136. ----
#define VST 136   // u16 row stride for 128-o window
__global__ __launch_bounds__(256, 3) void k_out(const float* __restrict__ ws,
                                                void* __restrict__ outp) {
  __shared__ unsigned short tileV[192*VST];    // 52.2 KB
  int b = blockIdx.z, bp = blockIdx.y;         // bp in [0,4): o-base bp*128
  int bx = blockIdx.x;                         // 0..48: 64-px strip
  int tid = threadIdx.x;
  int w = tid >> 6, lane = tid & 63, q = lane >> 4, l16 = lane & 15;
  int pix0 = bx*64;
  int h00 = pix0 / WD, w00 = pix0 - h00*WD;
  int wstart = (h00+1)*PW + (w00+1) - (PW+1);
  int pix = pix0 + w*16 + l16;
  float sc[8], ba[8];
#pragma unroll
  for (int j = 0; j < 8; j++) {
    int m = q*8 + j;
    sc[j] = ws[OFF_SC2 + m];
    ba[j] = sc[j]*ws[OFF_B1F + m] + ws[OFF_SH2 + m];
  }
  const unsigned short* hqt = (const unsigned short*)(ws + OFF_HQT) + (size_t)b*HWP*MIDM;
  const unsigned short* gkt = (const unsigned short*)(ws + OFF_GKT) + (size_t)b*PADP*MIDM;
  int h0 = pix / WD, w0 = pix - h0*WD;
  short8 Bf[9];
  {
    short8 th = *(const short8*)(hqt + (size_t)pix*MIDM + q*8);
    float hv[8];
#pragma unroll
    for (int j = 0; j < 8; j++) hv[j] = b2f((unsigned short)th[j]);
    const unsigned short* gkb = gkt + ((size_t)h0*PW + w0)*MIDM + q*8;
#pragma unroll
    for (int p = 0; p < 9; p++) {
      short8 tg = *(const short8*)(gkb + (size_t)((p/3)*PW + (p - (p/3)*3))*MIDM);
#pragma unroll
      for (int j = 0; j < 8; j++)
        Bf[p][j] = (short)f2b(fmaxf(sc[j]*(hv[j] + b2f((unsigned short)tg[j])) + ba[j], 0.f));
    }
  }
  // stage vt window: 192 pps x 128 o, as 3072 short8 (16 B) chunks
  const unsigned short* vsrc = (const unsigned short*)(ws + OFF_VT)
      + (size_t)b*PADP*OGN + (size_t)bp*128;
#pragma unroll
  for (int i = 0; i < 12; i++) {
    int u = i*256 + tid;                  // 0..3071
    int wp = u >> 4, col = (u & 15)*8;    // 192 rows x 16 chunks x 8 u16
    *(short8*)&tileV[wp*VST + col] =
        *(const short8*)(vsrc + (size_t)(wstart + wp)*OGN + col);
  }
  const bool isbf = ws[OFF_FLAG] > 0.5f;
  const float2* pq = (const float2*)(ws + OFF_PQ) + b*OGN;
  const unsigned short* ABb = (const unsigned short*)(ws + OFF_AB)
      + ((size_t)b*OGN + bp*128)*MIDM;
  const int doff[9] = {-PW-1, -PW, -PW+1, -1, 0, 1, PW-1, PW, PW+1};
  int ppl = (h0+1)*PW + (w0+1) - wstart;
  __syncthreads();
  for (int byv = 0; byv < 2; ++byv) {
    short8 A[4];
    f32x4 Qv[4];
#pragma unroll
    for (int ot = 0; ot < 4; ot++) {
      A[ot] = *(const short8*)(ABb + (size_t)(byv*64 + ot*16 + l16)*MIDM + q*8);
      int o0 = bp*128 + byv*64 + ot*16 + q*4;
      f32x4 qv = { pq[o0+0].y, pq[o0+1].y, pq[o0+2].y, pq[o0+3].y };
      Qv[ot] = qv;
    }
    float acc[4] = {0.f, 0.f, 0.f, 0.f};
#pragma unroll
    for (int p = 0; p < 9; p++) {
      int lp = ppl + doff[p];
      const unsigned short* vrow = &tileV[lp*VST + byv*64];
#pragma unroll
      for (int ot = 0; ot < 4; ot++) {
        f32x4 c = {0.f, 0.f, 0.f, 0.f};
        c = mfma16(A[ot], Bf[p], c);
        ushort4 vv = *(const ushort4*)(vrow + ot*16 + q*4);
        acc[ot] += (c[0] + Qv[ot][0])*b2f(vv.x) + (c[1] + Qv[ot][1])*b2f(vv.y)
                 + (c[2] + Qv[ot][2])*b2f(vv.z) + (c[3] + Qv[ot][3])*b2f(vv.w);
      }
    }
#pragma unroll
    for (int ot = 0; ot < 4; ot++) {
      int co = bp*32 + byv*16 + ot*4 + q;
      size_t oidx = ((size_t)b*128 + co)*HWP + pix;
      if (isbf) __builtin_nontemporal_store(f2b(acc[ot]), (unsigned short*)outp + oidx);
      else      __builtin_nontemporal_store(acc[ot], (float*)outp + oidx);
    }
  }
}

extern "C" void kernel_launch(void* const* d_in, const int* in_sizes, int n_in,
                              void* d_out, int out_size, void* d_ws, size_t ws_size,
                              hipStream_t stream) {
  float* ws = (float*)d_ws;
  hipLaunchKernelGGL(k_prep, dim3(420), dim3(256), 0, stream,
                     d_in[0], d_in[1], d_in[2], d_in[3], d_in[4], d_in[5],
                     d_in[6], d_in[7], d_in[8], d_in[9], d_in[10], d_in[11],
                     d_in[12], d_in[13], d_in[14], d_in[15], d_in[16],
                     d_in[17], d_in[18], d_in[19], d_in[20], ws);
  hipLaunchKernelGGL(k_mid,  dim3(980),      dim3(256), 0, stream, ws);
  hipLaunchKernelGGL(k_gramh,dim3(32, 4),    dim3(256), 0, stream, ws);
  hipLaunchKernelGGL(k_stats,dim3(4),        dim3(512), 0, stream, ws);
  hipLaunchKernelGGL(k_out,  dim3(49, 4, 4), dim3(256), 0, stream, ws, d_out);
}